// Round 21
// baseline (5653.849 us; speedup 1.0000x reference)
//
#include <hip/hip_runtime.h>
#include <hip/hip_fp16.h>
#include <math.h>

#define BB 8
#define TT 50
#define AA 1444      // A*A
#define HH 1024
#define G4 4096      // 4*H
#define INX 92416    // A*A*C
#define IND 93860    // INX + AA
#define INDP 93888   // IND padded to multiple of 32
#define NKB 2934     // INDP / 32
#define SEG 64       // balanced ij segments in contract

typedef unsigned int u32;
typedef unsigned short u16;
typedef u32 u32x4 __attribute__((ext_vector_type(4)));
typedef short s16x8 __attribute__((ext_vector_type(8)));   // 8 bf16
typedef float f32x4 __attribute__((ext_vector_type(4)));

__device__ __forceinline__ float sigf(float x) { return 1.0f / (1.0f + expf(-x)); }

__device__ __forceinline__ u16 f2bf(float f) {
    u32 u = __float_as_uint(f);
    u = (u + 0x7FFFu + ((u >> 16) & 1u)) >> 16;
    return (u16)u;
}
__device__ __forceinline__ u16 f2h(float f) { return __half_as_ushort(__float2half(f)); }
__device__ __forceinline__ float h2f(u16 h) { return __half2float(__ushort_as_half(h)); }

// ---------------------------------------------------------------------------
// K0: zero recurrent state
__global__ void k_init(float* __restrict__ h, float* __restrict__ c0,
                       float* __restrict__ c1, float* __restrict__ att) {
    int i = blockIdx.x * 256 + threadIdx.x;
    if (i < BB * HH) { h[i] = 0.f; c0[i] = 0.f; c1[i] = 0.f; }
    if (i < BB * AA) att[i] = 0.f;
}

// ---------------------------------------------------------------------------
// K-cvtswz: W_ih f32 -> bf16 in MFMA A-fragment order (proven R5-R16).
__global__ __launch_bounds__(256)
void k_cvtswz(const float* __restrict__ W, u16* __restrict__ Wf) {
    const size_t idx = (size_t)blockIdx.x * 256 + threadIdx.x;
    const int l = (int)(idx & 63);
    const size_t mkb = idx >> 6;
    const int kb = (int)(mkb % NKB);
    const int m = (int)(mkb / NKB);
    const int row = m * 16 + (l & 15);
    const int k0 = kb * 32 + ((l >> 4) << 3);
    union { u16 s[8]; u32x4 v; } pk;
    if (k0 + 8 <= IND) {
        const float* src = W + (size_t)row * IND + k0;
        float4 a = *(const float4*)src;
        float4 b = *(const float4*)(src + 4);
        pk.s[0] = f2bf(a.x); pk.s[1] = f2bf(a.y);
        pk.s[2] = f2bf(a.z); pk.s[3] = f2bf(a.w);
        pk.s[4] = f2bf(b.x); pk.s[5] = f2bf(b.y);
        pk.s[6] = f2bf(b.z); pk.s[7] = f2bf(b.w);
    } else {
#pragma unroll
        for (int j = 0; j < 8; ++j) {
            const int k = k0 + j;
            pk.s[j] = (k < IND) ? f2bf(W[(size_t)row * IND + k]) : (u16)0;
        }
    }
    *(u32x4*)(Wf + idx * 8) = pk.v;
}

// ---------------------------------------------------------------------------
// K-gm: gm[t][b][g] = sum_k Wm[g][k] * m[b][t][k]   (full f32, once)
__global__ __launch_bounds__(512)
void k_gm(const float* __restrict__ W, const float* __restrict__ masks,
          float* __restrict__ gm) {
    const int g0 = blockIdx.x * 8;
    const int n = threadIdx.x;
    if (n >= BB * TT) return;
    const int b = n & 7, t = n >> 3;
    const float* mp = masks + ((size_t)b * TT + t) * AA;
    const float* wr[8];
#pragma unroll
    for (int r = 0; r < 8; ++r) wr[r] = W + (size_t)(g0 + r) * IND + INX;
    float acc[8];
#pragma unroll
    for (int r = 0; r < 8; ++r) acc[r] = 0.f;
    for (int k = 0; k < AA; ++k) {
        const float mv = mp[k];
#pragma unroll
        for (int r = 0; r < 8; ++r) acc[r] = fmaf(wr[r][k], mv, acc[r]);
    }
#pragma unroll
    for (int r = 0; r < 8; ++r)
        gm[((size_t)t * BB + b) * G4 + g0 + r] = acc[r];
}

// ---------------------------------------------------------------------------
// K-pre: Y[t][ij][gc][b][gl] (fp16) = sum_c W[g][ij*64+c] * x[b][t][ij][c]
// 2 bt-tiles per sync group (13 pairs covering 25 tiles): fewer barriers,
// 2x memory ops in flight per phase. MFMA order per tile unchanged vs R16.
__global__ __launch_bounds__(256)
void k_pre(const u16* __restrict__ Wf, const float* __restrict__ x,
           u16* __restrict__ Y) {
    const int ij = blockIdx.x >> 4;
    const int gc = blockIdx.x & 15;
    const int tid = threadIdx.x;
    const int w = tid >> 6, l = tid & 63;
    __shared__ u16 xs[2][1024];   // [tile][16 col][64 c] bf16, ^=(col&7)<<4
    __shared__ u16 os[2][4096];   // [tile][16 n][256 g] fp16, ^=(n&7)<<4

    s16x8 a[4][2];
#pragma unroll
    for (int q = 0; q < 4; ++q) {
        const size_t m = (size_t)gc * 16 + w * 4 + q;
#pragma unroll
        for (int kb = 0; kb < 2; ++kb)
            a[q][kb] = __builtin_nontemporal_load(
                (const s16x8*)(Wf + (m * NKB + (size_t)ij * 2 + kb) * 512 + l * 8));
    }

    const int scol = tid >> 4, scg = tid & 15;
    for (int p = 0; p < 13; ++p) {
        const int nt0 = 2 * p;
        const int nt1 = 2 * p + 1;
        const bool has1 = (nt1 < 25);
        // ---- stage x tiles
#pragma unroll
        for (int s = 0; s < 2; ++s) {
            const int nt = nt0 + s;
            if (s == 1 && !has1) break;
            const int n = nt * 16 + scol;
            const int b = n & 7, t = n >> 3;
            char* xsb = (char*)xs[s];
            float4 v = *(const float4*)(x + (((size_t)b * TT + t) * AA + ij) * 64 + scg * 4);
            u32 lo = ((u32)f2bf(v.y) << 16) | f2bf(v.x);
            u32 hi = ((u32)f2bf(v.w) << 16) | f2bf(v.z);
            const int addr = (scol * 128 + scg * 8) ^ ((scol & 7) << 4);
            *(u32*)(xsb + addr) = lo;
            *(u32*)(xsb + addr + 4) = hi;
        }
        __syncthreads();
        // ---- MFMA both tiles -> os
#pragma unroll
        for (int s = 0; s < 2; ++s) {
            char* xsb = (char*)xs[s];
            char* osb = (char*)os[s];
            f32x4 acc[4];
            {
                const int col = l & 15;
                const int c0b = (l >> 4) * 16;
                const int swz = (col & 7) << 4;
                s16x8 b0 = *(const s16x8*)(xsb + ((col * 128 + c0b) ^ swz));
                s16x8 b1 = *(const s16x8*)(xsb + ((col * 128 + 64 + c0b) ^ swz));
#pragma unroll
                for (int q = 0; q < 4; ++q) {
                    acc[q] = (f32x4){0.f, 0.f, 0.f, 0.f};
                    acc[q] = __builtin_amdgcn_mfma_f32_16x16x32_bf16(a[q][0], b0, acc[q], 0, 0, 0);
                    acc[q] = __builtin_amdgcn_mfma_f32_16x16x32_bf16(a[q][1], b1, acc[q], 0, 0, 0);
                }
            }
            {
                const int nrow = l & 15;
                const int swz = (nrow & 7) << 4;
#pragma unroll
                for (int q = 0; q < 4; ++q) {
                    u32 lo = ((u32)f2h(acc[q][1]) << 16) | f2h(acc[q][0]);
                    u32 hi = ((u32)f2h(acc[q][3]) << 16) | f2h(acc[q][2]);
                    const int addr = (nrow * 512 + w * 128 + q * 32 + (l >> 4) * 8) ^ swz;
                    *(u32*)(osb + addr) = lo;
                    *(u32*)(osb + addr + 4) = hi;
                }
            }
        }
        __syncthreads();
        // ---- write Y chunks
#pragma unroll
        for (int s = 0; s < 2; ++s) {
            const int nt = nt0 + s;
            if (s == 1 && !has1) break;
            char* osb = (char*)os[s];
            const int n = nt * 16 + scol;
            const int b = n & 7, t = n >> 3;
            const int swz = (scol & 7) << 4;
            u32x4 d0 = *(const u32x4*)(osb + ((scol * 512 + scg * 32) ^ swz));
            u32x4 d1 = *(const u32x4*)(osb + ((scol * 512 + scg * 32 + 16) ^ swz));
            u16* yp = Y + ((((size_t)t * AA + ij) * 16 + gc) * 8 + b) * 256 + scg * 16;
            __builtin_nontemporal_store(d0, (u32x4*)yp);
            __builtin_nontemporal_store(d1, (u32x4*)(yp + 8));
        }
        __syncthreads();
    }
}

// ---------------------------------------------------------------------------
// K-contract: blocks [0,512): (seg,b) partials over balanced ij segments:
//   part[seg][b][g] = sum_{ij in seg} att[b][ij] * Y[t][ij][gc(g)][b][gl(g)]
// blocks [512,768): gates2 = Whh @ h (f32)
__global__ __launch_bounds__(512)
void k_contract(const u16* __restrict__ Y, const float* __restrict__ att,
                const float* __restrict__ Whh, const float* __restrict__ h,
                float* __restrict__ part, float* __restrict__ gates2, int t) {
    const int w = threadIdx.x >> 6, l = threadIdx.x & 63;
    if (blockIdx.x < 512) {
        const int seg = blockIdx.x >> 3, b = blockIdx.x & 7;
        const int ij0 = (seg * AA) >> 6, ij1 = ((seg + 1) * AA) >> 6;
        const int g0 = threadIdx.x * 8;
        float acc[8];
#pragma unroll
        for (int k = 0; k < 8; ++k) acc[k] = 0.f;
        const u16* yp = Y + ((((size_t)t * AA + ij0) * 16 + (g0 >> 8)) * 8 + b) * 256
                      + (g0 & 255);
        const float* ap = att + b * AA;
        const size_t ystride = (size_t)16 * 8 * 256;  // per-ij stride = 32768
        int ij = ij0;
        for (; ij + 4 <= ij1; ij += 4) {
            const float am0 = ap[ij];
            const float am1 = ap[ij + 1];
            const float am2 = ap[ij + 2];
            const float am3 = ap[ij + 3];
            u32x4 v0 = __builtin_nontemporal_load((const u32x4*)yp);
            u32x4 v1 = __builtin_nontemporal_load((const u32x4*)(yp + ystride));
            u32x4 v2 = __builtin_nontemporal_load((const u32x4*)(yp + 2 * ystride));
            u32x4 v3 = __builtin_nontemporal_load((const u32x4*)(yp + 3 * ystride));
            const u16* s0 = (const u16*)&v0;
            const u16* s1 = (const u16*)&v1;
            const u16* s2 = (const u16*)&v2;
            const u16* s3 = (const u16*)&v3;
#pragma unroll
            for (int k = 0; k < 8; ++k) acc[k] = fmaf(am0, h2f(s0[k]), acc[k]);
#pragma unroll
            for (int k = 0; k < 8; ++k) acc[k] = fmaf(am1, h2f(s1[k]), acc[k]);
#pragma unroll
            for (int k = 0; k < 8; ++k) acc[k] = fmaf(am2, h2f(s2[k]), acc[k]);
#pragma unroll
            for (int k = 0; k < 8; ++k) acc[k] = fmaf(am3, h2f(s3[k]), acc[k]);
            yp += 4 * ystride;
        }
        for (; ij < ij1; ++ij) {
            const float am0 = ap[ij];
            u32x4 v0 = __builtin_nontemporal_load((const u32x4*)yp);
            const u16* s0 = (const u16*)&v0;
#pragma unroll
            for (int k = 0; k < 8; ++k) acc[k] = fmaf(am0, h2f(s0[k]), acc[k]);
            yp += ystride;
        }
        float* pp = part + ((size_t)seg * BB + b) * G4 + g0;
#pragma unroll
        for (int k = 0; k < 8; ++k) pp[k] = acc[k];
    } else {
        // recurrent GEMV: 16 rows per block, 2 rows per wave
        const int g0 = (blockIdx.x - 512) * 16 + w * 2;
        float acc[2][8];
#pragma unroll
        for (int r = 0; r < 2; ++r)
#pragma unroll
            for (int b = 0; b < 8; ++b) acc[r][b] = 0.f;
#pragma unroll 4
        for (int i = 0; i < 16; ++i) {
            const int j = l + 64 * i;
            float hv[8];
#pragma unroll
            for (int b = 0; b < 8; ++b) hv[b] = h[b * HH + j];
#pragma unroll
            for (int r = 0; r < 2; ++r) {
                const float w0 = Whh[(size_t)(g0 + r) * HH + j];
#pragma unroll
                for (int b = 0; b < 8; ++b) acc[r][b] = fmaf(w0, hv[b], acc[r][b]);
            }
        }
#pragma unroll
        for (int r = 0; r < 2; ++r)
#pragma unroll
            for (int b = 0; b < 8; ++b) {
                float v = acc[r][b];
                for (int off = 32; off; off >>= 1) v += __shfl_down(v, off, 64);
                if (l == 0) gates2[b * G4 + g0 + r] = v;
            }
    }
}

// ---------------------------------------------------------------------------
// K-cell3: gates = sum_seg part + gm[t] + gates2 + biases -> LSTM cell
__global__ __launch_bounds__(512)
void k_cell3(const float* __restrict__ part, const float* __restrict__ gm,
             const float* __restrict__ gates2, const float* __restrict__ bih,
             const float* __restrict__ bhh, const float* __restrict__ c_in,
             float* __restrict__ c_out, float* __restrict__ h,
             float* __restrict__ hrelu, int t) {
    const int i = blockIdx.x * 512 + threadIdx.x;  // 0..8191
    const int b = i >> 10, j = i & (HH - 1);
    float g[4];
#pragma unroll
    for (int r = 0; r < 4; ++r) {
        const int gg = r * HH + j;
        float s = 0.f;
        for (int sg = 0; sg < SEG; ++sg)
            s += part[((size_t)sg * BB + b) * G4 + gg];
        g[r] = s + gm[((size_t)t * BB + b) * G4 + gg] + gates2[b * G4 + gg]
             + bih[gg] + bhh[gg];
    }
    const float ig = sigf(g[0]);
    const float fg = sigf(g[1]);
    const float gv = tanhf(g[2]);
    const float og = sigf(g[3]);
    const float cn = fg * c_in[i] + ig * gv;
    const float hn = og * tanhf(cn);
    c_out[i] = cn;
    h[i] = hn;
    hrelu[i] = fmaxf(hn, 0.f);
}

// ---------------------------------------------------------------------------
// K-post2: blocks [0,181): out(t) rows; blocks [181,362): att(t+1) rows.
__global__ __launch_bounds__(512)
void k_post2(const float* __restrict__ hrelu,
             const float* __restrict__ Watt, const float* __restrict__ batt,
             const float* __restrict__ Wout, const float* __restrict__ bout,
             float* __restrict__ att, float* __restrict__ out, int t) {
    __shared__ float hr[BB][HH];
    for (int i = threadIdx.x; i < BB * HH; i += 512)
        hr[i >> 10][i & (HH - 1)] = hrelu[i];
    __syncthreads();
    const int w = threadIdx.x >> 6, l = threadIdx.x & 63;
    const bool isOut = blockIdx.x < 181;
    if (!isOut && t + 1 >= TT) return;
    const int row = (isOut ? blockIdx.x : (blockIdx.x - 181)) * 8 + w;
    if (row >= AA) return;
    const float* W = isOut ? Wout : Watt;
    float acc[8];
#pragma unroll
    for (int b = 0; b < 8; ++b) acc[b] = 0.f;
#pragma unroll 4
    for (int i = 0; i < 16; ++i) {
        const int j = l + 64 * i;
        const float w0 = W[(size_t)row * HH + j];
#pragma unroll
        for (int b = 0; b < 8; ++b) acc[b] = fmaf(w0, hr[b][j], acc[b]);
    }
#pragma unroll
    for (int b = 0; b < 8; ++b) {
        float v = acc[b];
        for (int off = 32; off; off >>= 1) v += __shfl_xor(v, off, 64);
        acc[b] = v;
    }
    if (l < 8) {
        if (isOut)
            out[((size_t)l * TT + t) * AA + row] = sigf(acc[l] + bout[row]);
        else
            att[l * AA + row] = sigf(acc[l] + batt[row]);
    }
}

// ---------------------------------------------------------------------------
// Fallback f32 path (validated round 1) if ws is too small.
__global__ __launch_bounds__(256, 2)
void k_gates_f32(const float* __restrict__ x, const float* __restrict__ masks,
                 const float* __restrict__ Wih, const float* __restrict__ Whh,
                 const float* __restrict__ bih, const float* __restrict__ bhh,
                 const float* __restrict__ h, const float* __restrict__ att,
                 float* __restrict__ gates, int t) {
    __shared__ float att_s[BB * AA];
    const int tid = threadIdx.x;
    for (int i = tid; i < BB * AA; i += 256) att_s[i] = att[i];
    __syncthreads();
    const int g0 = blockIdx.x * 8;
    float acc[8][8];
#pragma unroll
    for (int r = 0; r < 8; ++r)
#pragma unroll
        for (int b = 0; b < 8; ++b) acc[r][b] = 0.f;
    const float* xb = x + (size_t)t * INX;
    for (int k = tid; k < INX; k += 256) {
        const int ij = k >> 6;
        float xa[8];
#pragma unroll
        for (int b = 0; b < 8; ++b)
            xa[b] = xb[(size_t)b * TT * INX + k] * att_s[b * AA + ij];
#pragma unroll
        for (int r = 0; r < 8; ++r) {
            float w = __builtin_nontemporal_load(&Wih[(size_t)(g0 + r) * IND + k]);
#pragma unroll
            for (int b = 0; b < 8; ++b) acc[r][b] = fmaf(w, xa[b], acc[r][b]);
        }
    }
    const float* mb = masks + (size_t)t * AA;
    for (int k = tid; k < AA; k += 256) {
        float mv[8];
#pragma unroll
        for (int b = 0; b < 8; ++b) mv[b] = mb[(size_t)b * TT * AA + k];
#pragma unroll
        for (int r = 0; r < 8; ++r) {
            float w = __builtin_nontemporal_load(&Wih[(size_t)(g0 + r) * IND + INX + k]);
#pragma unroll
            for (int b = 0; b < 8; ++b) acc[r][b] = fmaf(w, mv[b], acc[r][b]);
        }
    }
    for (int j = tid; j < HH; j += 256) {
        float hv[8];
#pragma unroll
        for (int b = 0; b < 8; ++b) hv[b] = h[b * HH + j];
#pragma unroll
        for (int r = 0; r < 8; ++r) {
            float w = Whh[(size_t)(g0 + r) * HH + j];
#pragma unroll
            for (int b = 0; b < 8; ++b) acc[r][b] = fmaf(w, hv[b], acc[r][b]);
        }
    }
#pragma unroll
    for (int r = 0; r < 8; ++r)
#pragma unroll
        for (int b = 0; b < 8; ++b) {
            float v = acc[r][b];
            for (int off = 32; off; off >>= 1) v += __shfl_down(v, off, 64);
            acc[r][b] = v;
        }
    __shared__ float red[4][8][8];
    const int wave = tid >> 6, lane = tid & 63;
    if (lane == 0) {
#pragma unroll
        for (int r = 0; r < 8; ++r)
#pragma unroll
            for (int b = 0; b < 8; ++b) red[wave][r][b] = acc[r][b];
    }
    __syncthreads();
    if (tid < 64) {
        const int r = tid >> 3, b = tid & 7;
        const int g = g0 + r;
        float v = red[0][r][b] + red[1][r][b] + red[2][r][b] + red[3][r][b];
        gates[b * G4 + g] = v + bih[g] + bhh[g];
    }
}

__global__ void k_cell(const float* __restrict__ gates, float* __restrict__ c,
                       float* __restrict__ h, float* __restrict__ hrelu) {
    int idx = blockIdx.x * 256 + threadIdx.x;
    if (idx >= BB * HH) return;
    const int b = idx >> 10, j = idx & (HH - 1);
    const float* gb = gates + b * G4;
    float ig = sigf(gb[j]);
    float fg = sigf(gb[HH + j]);
    float gg = tanhf(gb[2 * HH + j]);
    float og = sigf(gb[3 * HH + j]);
    float cn = fg * c[idx] + ig * gg;
    float hn = og * tanhf(cn);
    c[idx] = cn;
    h[idx] = hn;
    hrelu[idx] = fmaxf(hn, 0.f);
}

__global__ __launch_bounds__(256)
void k_attout(const float* __restrict__ hrelu,
              const float* __restrict__ Watt, const float* __restrict__ batt,
              const float* __restrict__ Wout, const float* __restrict__ bout,
              float* __restrict__ att, float* __restrict__ out, int t) {
    const int wid = blockIdx.x * 4 + (threadIdx.x >> 6);
    const int lane = threadIdx.x & 63;
    if (wid >= 2 * AA) return;
    const bool isAtt = wid < AA;
    const int row = isAtt ? wid : wid - AA;
    const float* W = isAtt ? Watt : Wout;
    float acc[8];
#pragma unroll
    for (int b = 0; b < 8; ++b) acc[b] = 0.f;
    for (int j = lane; j < HH; j += 64) {
        const float w = W[(size_t)row * HH + j];
#pragma unroll
        for (int b = 0; b < 8; ++b) acc[b] = fmaf(w, hrelu[b * HH + j], acc[b]);
    }
#pragma unroll
    for (int b = 0; b < 8; ++b) {
        float v = acc[b];
        for (int off = 32; off; off >>= 1) v += __shfl_xor(v, off, 64);
        acc[b] = v;
    }
    if (lane < 8) {
        const int b = lane;
        if (isAtt)
            att[b * AA + row] = sigf(acc[b] + batt[row]);
        else
            out[((size_t)b * TT + t) * AA + row] = sigf(acc[b] + bout[row]);
    }
}

// ---------------------------------------------------------------------------
extern "C" void kernel_launch(void* const* d_in, const int* in_sizes, int n_in,
                              void* d_out, int out_size, void* d_ws, size_t ws_size,
                              hipStream_t stream) {
    const float* tensors = (const float*)d_in[0];
    const float* masks   = (const float*)d_in[1];
    const float* Wih     = (const float*)d_in[2];
    const float* Whh     = (const float*)d_in[3];
    const float* bih     = (const float*)d_in[4];
    const float* bhh     = (const float*)d_in[5];
    const float* Watt    = (const float*)d_in[6];
    const float* batt    = (const float*)d_in[7];
    const float* Wout    = (const float*)d_in[8];
    const float* bout    = (const float*)d_in[9];
    float* out = (float*)d_out;

    float* ws     = (float*)d_ws;
    float* h      = ws;                    // 8192
    float* c0     = h + BB * HH;           // 8192
    float* c1     = c0 + BB * HH;          // 8192
    float* hrelu  = c1 + BB * HH;          // 8192
    float* gates2 = hrelu + BB * HH;       // 32768
    float* att    = gates2 + BB * G4;      // 11552
    float* part   = att + BB * AA;         // 64*8*4096 = 2097152
    float* gm     = part + (size_t)SEG * BB * G4;  // 50*8*4096 = 1638400
    u16*   Wf     = (u16*)(gm + (size_t)TT * BB * G4);   // 769.1 MB
    u16*   Y      = Wf + (size_t)G4 * INDP;              // 4.73 GB

    const size_t f32_cnt = (size_t)(4 * BB * HH + BB * G4 + BB * AA)
                         + (size_t)SEG * BB * G4 + (size_t)TT * BB * G4;
    const size_t need = f32_cnt * 4 + (size_t)G4 * INDP * 2
                      + (size_t)TT * AA * BB * G4 * 2;
    const bool fast_path = ws_size >= need;

    k_init<<<46, 256, 0, stream>>>(h, c0, c1, att);
    if (fast_path) {
        k_cvtswz<<<NKB * 64, 256, 0, stream>>>(Wih, Wf);
        k_gm<<<512, 512, 0, stream>>>(Wih, masks, gm);
        k_pre<<<AA * 16, 256, 0, stream>>>(Wf, tensors, Y);
        for (int t = 0; t < TT; ++t) {
            float* cin  = (t & 1) ? c1 : c0;
            float* cout = (t & 1) ? c0 : c1;
            k_contract<<<768, 512, 0, stream>>>(Y, att, Whh, h, part, gates2, t);
            k_cell3<<<16, 512, 0, stream>>>(part, gm, gates2, bih, bhh, cin,
                                            cout, h, hrelu, t);
            k_post2<<<362, 512, 0, stream>>>(hrelu, Watt, batt, Wout, bout,
                                             att, out, t);
        }
    } else {
        for (int t = 0; t < TT; ++t) {
            k_gates_f32<<<512, 256, 0, stream>>>(tensors, masks, Wih, Whh, bih,
                                                 bhh, h, att, part, t);
            k_cell<<<32, 256, 0, stream>>>(part, c0, h, hrelu);
            k_attout<<<722, 256, 0, stream>>>(hrelu, Watt, batt, Wout, bout,
                                              att, out, t);
        }
    }
}

// Round 22
// 4450.232 us; speedup vs baseline: 1.2705x; 1.2705x over previous
//
#include <hip/hip_runtime.h>
#include <hip/hip_fp16.h>
#include <math.h>

#define BB 8
#define TT 50
#define AA 1444      // A*A
#define HH 1024
#define G4 4096      // 4*H
#define INX 92416    // A*A*C
#define IND 93860    // INX + AA
#define INDP 93888   // IND padded to multiple of 32
#define NKB 2934     // INDP / 32
#define SEG 64       // balanced ij segments in contract

typedef unsigned int u32;
typedef unsigned short u16;
typedef u32 u32x4 __attribute__((ext_vector_type(4)));
typedef short s16x8 __attribute__((ext_vector_type(8)));   // 8 bf16
typedef float f32x4 __attribute__((ext_vector_type(4)));

__device__ __forceinline__ float sigf(float x) { return 1.0f / (1.0f + expf(-x)); }

__device__ __forceinline__ u16 f2bf(float f) {
    u32 u = __float_as_uint(f);
    u = (u + 0x7FFFu + ((u >> 16) & 1u)) >> 16;
    return (u16)u;
}
__device__ __forceinline__ u16 f2h(float f) { return __half_as_ushort(__float2half(f)); }
__device__ __forceinline__ float h2f(u16 h) { return __half2float(__ushort_as_half(h)); }

// ---------------------------------------------------------------------------
// K0: zero recurrent state
__global__ void k_init(float* __restrict__ h, float* __restrict__ c0,
                       float* __restrict__ c1, float* __restrict__ att) {
    int i = blockIdx.x * 256 + threadIdx.x;
    if (i < BB * HH) { h[i] = 0.f; c0[i] = 0.f; c1[i] = 0.f; }
    if (i < BB * AA) att[i] = 0.f;
}

// ---------------------------------------------------------------------------
// K-cvtswz: W_ih f32 -> bf16 in MFMA A-fragment order (proven R5-R16).
__global__ __launch_bounds__(256)
void k_cvtswz(const float* __restrict__ W, u16* __restrict__ Wf) {
    const size_t idx = (size_t)blockIdx.x * 256 + threadIdx.x;
    const int l = (int)(idx & 63);
    const size_t mkb = idx >> 6;
    const int kb = (int)(mkb % NKB);
    const int m = (int)(mkb / NKB);
    const int row = m * 16 + (l & 15);
    const int k0 = kb * 32 + ((l >> 4) << 3);
    union { u16 s[8]; u32x4 v; } pk;
    if (k0 + 8 <= IND) {
        const float* src = W + (size_t)row * IND + k0;
        float4 a = *(const float4*)src;
        float4 b = *(const float4*)(src + 4);
        pk.s[0] = f2bf(a.x); pk.s[1] = f2bf(a.y);
        pk.s[2] = f2bf(a.z); pk.s[3] = f2bf(a.w);
        pk.s[4] = f2bf(b.x); pk.s[5] = f2bf(b.y);
        pk.s[6] = f2bf(b.z); pk.s[7] = f2bf(b.w);
    } else {
#pragma unroll
        for (int j = 0; j < 8; ++j) {
            const int k = k0 + j;
            pk.s[j] = (k < IND) ? f2bf(W[(size_t)row * IND + k]) : (u16)0;
        }
    }
    *(u32x4*)(Wf + idx * 8) = pk.v;
}

// ---------------------------------------------------------------------------
// K-gm: gm[t][b][g] = sum_k Wm[g][k] * m[b][t][k]   (full f32, once)
__global__ __launch_bounds__(512)
void k_gm(const float* __restrict__ W, const float* __restrict__ masks,
          float* __restrict__ gm) {
    const int g0 = blockIdx.x * 8;
    const int n = threadIdx.x;
    if (n >= BB * TT) return;
    const int b = n & 7, t = n >> 3;
    const float* mp = masks + ((size_t)b * TT + t) * AA;
    const float* wr[8];
#pragma unroll
    for (int r = 0; r < 8; ++r) wr[r] = W + (size_t)(g0 + r) * IND + INX;
    float acc[8];
#pragma unroll
    for (int r = 0; r < 8; ++r) acc[r] = 0.f;
    for (int k = 0; k < AA; ++k) {
        const float mv = mp[k];
#pragma unroll
        for (int r = 0; r < 8; ++r) acc[r] = fmaf(wr[r][k], mv, acc[r]);
    }
#pragma unroll
    for (int r = 0; r < 8; ++r)
        gm[((size_t)t * BB + b) * G4 + g0 + r] = acc[r];
}

// ---------------------------------------------------------------------------
// K-pre: Y[t][ij][b][g] (fp16) = sum_c W[g][ij*64+c] * x[b][t][ij][c]
// (R14/R16-proven: Wf bf16 fragments, 25 bt-tiles, LDS transpose out.)
__global__ __launch_bounds__(256)
void k_pre(const u16* __restrict__ Wf, const float* __restrict__ x,
           u16* __restrict__ Y) {
    const int ij = blockIdx.x >> 4;
    const int gc = blockIdx.x & 15;
    const int tid = threadIdx.x;
    const int w = tid >> 6, l = tid & 63;
    __shared__ u16 xs[1024];   // [16 col][64 c] bf16, byte ^= (col&7)<<4
    __shared__ u16 os[4096];   // [16 n][256 g] fp16, byte ^= (n&7)<<4
    char* xsb = (char*)xs;
    char* osb = (char*)os;

    s16x8 a[4][2];
#pragma unroll
    for (int q = 0; q < 4; ++q) {
        const size_t m = (size_t)gc * 16 + w * 4 + q;
#pragma unroll
        for (int kb = 0; kb < 2; ++kb)
            a[q][kb] = __builtin_nontemporal_load(
                (const s16x8*)(Wf + (m * NKB + (size_t)ij * 2 + kb) * 512 + l * 8));
    }

    const int scol = tid >> 4, scg = tid & 15;
    for (int nt = 0; nt < 25; ++nt) {
        {
            const int n = nt * 16 + scol;
            const int b = n & 7, t = n >> 3;
            float4 v = *(const float4*)(x + (((size_t)b * TT + t) * AA + ij) * 64 + scg * 4);
            u32 lo = ((u32)f2bf(v.y) << 16) | f2bf(v.x);
            u32 hi = ((u32)f2bf(v.w) << 16) | f2bf(v.z);
            const int addr = (scol * 128 + scg * 8) ^ ((scol & 7) << 4);
            *(u32*)(xsb + addr) = lo;
            *(u32*)(xsb + addr + 4) = hi;
        }
        __syncthreads();
        f32x4 acc[4];
        {
            const int col = l & 15;
            const int c0b = (l >> 4) * 16;
            const int swz = (col & 7) << 4;
            s16x8 b0 = *(const s16x8*)(xsb + ((col * 128 + c0b) ^ swz));
            s16x8 b1 = *(const s16x8*)(xsb + ((col * 128 + 64 + c0b) ^ swz));
#pragma unroll
            for (int q = 0; q < 4; ++q) {
                acc[q] = (f32x4){0.f, 0.f, 0.f, 0.f};
                acc[q] = __builtin_amdgcn_mfma_f32_16x16x32_bf16(a[q][0], b0, acc[q], 0, 0, 0);
                acc[q] = __builtin_amdgcn_mfma_f32_16x16x32_bf16(a[q][1], b1, acc[q], 0, 0, 0);
            }
        }
        {
            const int nrow = l & 15;
            const int swz = (nrow & 7) << 4;
#pragma unroll
            for (int q = 0; q < 4; ++q) {
                u32 lo = ((u32)f2h(acc[q][1]) << 16) | f2h(acc[q][0]);
                u32 hi = ((u32)f2h(acc[q][3]) << 16) | f2h(acc[q][2]);
                const int addr = (nrow * 512 + w * 128 + q * 32 + (l >> 4) * 8) ^ swz;
                *(u32*)(osb + addr) = lo;
                *(u32*)(osb + addr + 4) = hi;
            }
        }
        __syncthreads();
        {
            const int n = nt * 16 + scol;
            const int b = n & 7, t = n >> 3;
            const int swz = (scol & 7) << 4;
            u32x4 d0 = *(const u32x4*)(osb + ((scol * 512 + scg * 32) ^ swz));
            u32x4 d1 = *(const u32x4*)(osb + ((scol * 512 + scg * 32 + 16) ^ swz));
            u16* yp = Y + (((size_t)t * AA + ij) * BB + b) * G4 + gc * 256 + scg * 16;
            *(u32x4*)yp = d0;
            *(u32x4*)(yp + 8) = d1;
        }
        __syncthreads();
    }
}

// ---------------------------------------------------------------------------
// K-contract: blocks [0,512): (seg,b) partials over balanced ij segments:
//   part[seg][b][g] = sum_{ij in seg} att[b][ij] * Y[t][ij][b][g]
// blocks [512,768): gates2 = Whh @ h (f32)
__global__ __launch_bounds__(512)
void k_contract(const u16* __restrict__ Y, const float* __restrict__ att,
                const float* __restrict__ Whh, const float* __restrict__ h,
                float* __restrict__ part, float* __restrict__ gates2, int t) {
    const int w = threadIdx.x >> 6, l = threadIdx.x & 63;
    if (blockIdx.x < 512) {
        const int seg = blockIdx.x >> 3, b = blockIdx.x & 7;
        const int ij0 = (seg * AA) >> 6, ij1 = ((seg + 1) * AA) >> 6;
        const int g0 = threadIdx.x * 8;
        float acc[8];
#pragma unroll
        for (int k = 0; k < 8; ++k) acc[k] = 0.f;
        const u16* yp = Y + (((size_t)t * AA + ij0) * BB + b) * G4 + g0;
        const float* ap = att + b * AA;
        int ij = ij0;
        for (; ij + 2 <= ij1; ij += 2) {
            const float am0 = ap[ij];
            const float am1 = ap[ij + 1];
            u32x4 v0 = __builtin_nontemporal_load((const u32x4*)yp);
            u32x4 v1 = __builtin_nontemporal_load((const u32x4*)(yp + (size_t)BB * G4));
            const u16* s0 = (const u16*)&v0;
            const u16* s1 = (const u16*)&v1;
#pragma unroll
            for (int k = 0; k < 8; ++k)
                acc[k] = fmaf(am0, h2f(s0[k]), acc[k]);
#pragma unroll
            for (int k = 0; k < 8; ++k)
                acc[k] = fmaf(am1, h2f(s1[k]), acc[k]);
            yp += (size_t)2 * BB * G4;
        }
        if (ij < ij1) {
            const float am0 = ap[ij];
            u32x4 v0 = __builtin_nontemporal_load((const u32x4*)yp);
            const u16* s0 = (const u16*)&v0;
#pragma unroll
            for (int k = 0; k < 8; ++k)
                acc[k] = fmaf(am0, h2f(s0[k]), acc[k]);
        }
        float* pp = part + ((size_t)seg * BB + b) * G4 + g0;
#pragma unroll
        for (int k = 0; k < 8; ++k) pp[k] = acc[k];
    } else {
        // recurrent GEMV: 16 rows per block, 2 rows per wave
        const int g0 = (blockIdx.x - 512) * 16 + w * 2;
        float acc[2][8];
#pragma unroll
        for (int r = 0; r < 2; ++r)
#pragma unroll
            for (int b = 0; b < 8; ++b) acc[r][b] = 0.f;
#pragma unroll 4
        for (int i = 0; i < 16; ++i) {
            const int j = l + 64 * i;
            float hv[8];
#pragma unroll
            for (int b = 0; b < 8; ++b) hv[b] = h[b * HH + j];
#pragma unroll
            for (int r = 0; r < 2; ++r) {
                const float w0 = Whh[(size_t)(g0 + r) * HH + j];
#pragma unroll
                for (int b = 0; b < 8; ++b) acc[r][b] = fmaf(w0, hv[b], acc[r][b]);
            }
        }
#pragma unroll
        for (int r = 0; r < 2; ++r)
#pragma unroll
            for (int b = 0; b < 8; ++b) {
                float v = acc[r][b];
                for (int off = 32; off; off >>= 1) v += __shfl_down(v, off, 64);
                if (l == 0) gates2[b * G4 + g0 + r] = v;
            }
    }
}

// ---------------------------------------------------------------------------
// K-cell3: gates = sum_seg part + gm[t] + gates2 + biases -> LSTM cell
__global__ __launch_bounds__(512)
void k_cell3(const float* __restrict__ part, const float* __restrict__ gm,
             const float* __restrict__ gates2, const float* __restrict__ bih,
             const float* __restrict__ bhh, const float* __restrict__ c_in,
             float* __restrict__ c_out, float* __restrict__ h,
             float* __restrict__ hrelu, int t) {
    const int i = blockIdx.x * 512 + threadIdx.x;  // 0..8191
    const int b = i >> 10, j = i & (HH - 1);
    float g[4];
#pragma unroll
    for (int r = 0; r < 4; ++r) {
        const int gg = r * HH + j;
        float s = 0.f;
        for (int sg = 0; sg < SEG; ++sg)
            s += part[((size_t)sg * BB + b) * G4 + gg];
        g[r] = s + gm[((size_t)t * BB + b) * G4 + gg] + gates2[b * G4 + gg]
             + bih[gg] + bhh[gg];
    }
    const float ig = sigf(g[0]);
    const float fg = sigf(g[1]);
    const float gv = tanhf(g[2]);
    const float og = sigf(g[3]);
    const float cn = fg * c_in[i] + ig * gv;
    const float hn = og * tanhf(cn);
    c_out[i] = cn;
    h[i] = hn;
    hrelu[i] = fmaxf(hn, 0.f);
}

// ---------------------------------------------------------------------------
// K-post2: blocks [0,181): out(t) rows; blocks [181,362): att(t+1) rows.
__global__ __launch_bounds__(512)
void k_post2(const float* __restrict__ hrelu,
             const float* __restrict__ Watt, const float* __restrict__ batt,
             const float* __restrict__ Wout, const float* __restrict__ bout,
             float* __restrict__ att, float* __restrict__ out, int t) {
    __shared__ float hr[BB][HH];
    for (int i = threadIdx.x; i < BB * HH; i += 512)
        hr[i >> 10][i & (HH - 1)] = hrelu[i];
    __syncthreads();
    const int w = threadIdx.x >> 6, l = threadIdx.x & 63;
    const bool isOut = blockIdx.x < 181;
    if (!isOut && t + 1 >= TT) return;
    const int row = (isOut ? blockIdx.x : (blockIdx.x - 181)) * 8 + w;
    if (row >= AA) return;
    const float* W = isOut ? Wout : Watt;
    float acc[8];
#pragma unroll
    for (int b = 0; b < 8; ++b) acc[b] = 0.f;
#pragma unroll 4
    for (int i = 0; i < 16; ++i) {
        const int j = l + 64 * i;
        const float w0 = W[(size_t)row * HH + j];
#pragma unroll
        for (int b = 0; b < 8; ++b) acc[b] = fmaf(w0, hr[b][j], acc[b]);
    }
#pragma unroll
    for (int b = 0; b < 8; ++b) {
        float v = acc[b];
        for (int off = 32; off; off >>= 1) v += __shfl_xor(v, off, 64);
        acc[b] = v;
    }
    if (l < 8) {
        if (isOut)
            out[((size_t)l * TT + t) * AA + row] = sigf(acc[l] + bout[row]);
        else
            att[l * AA + row] = sigf(acc[l] + batt[row]);
    }
}

// ---------------------------------------------------------------------------
// Fallback f32 path (validated round 1) if ws is too small.
__global__ __launch_bounds__(256, 2)
void k_gates_f32(const float* __restrict__ x, const float* __restrict__ masks,
                 const float* __restrict__ Wih, const float* __restrict__ Whh,
                 const float* __restrict__ bih, const float* __restrict__ bhh,
                 const float* __restrict__ h, const float* __restrict__ att,
                 float* __restrict__ gates, int t) {
    __shared__ float att_s[BB * AA];
    const int tid = threadIdx.x;
    for (int i = tid; i < BB * AA; i += 256) att_s[i] = att[i];
    __syncthreads();
    const int g0 = blockIdx.x * 8;
    float acc[8][8];
#pragma unroll
    for (int r = 0; r < 8; ++r)
#pragma unroll
        for (int b = 0; b < 8; ++b) acc[r][b] = 0.f;
    const float* xb = x + (size_t)t * INX;
    for (int k = tid; k < INX; k += 256) {
        const int ij = k >> 6;
        float xa[8];
#pragma unroll
        for (int b = 0; b < 8; ++b)
            xa[b] = xb[(size_t)b * TT * INX + k] * att_s[b * AA + ij];
#pragma unroll
        for (int r = 0; r < 8; ++r) {
            float w = __builtin_nontemporal_load(&Wih[(size_t)(g0 + r) * IND + k]);
#pragma unroll
            for (int b = 0; b < 8; ++b) acc[r][b] = fmaf(w, xa[b], acc[r][b]);
        }
    }
    const float* mb = masks + (size_t)t * AA;
    for (int k = tid; k < AA; k += 256) {
        float mv[8];
#pragma unroll
        for (int b = 0; b < 8; ++b) mv[b] = mb[(size_t)b * TT * AA + k];
#pragma unroll
        for (int r = 0; r < 8; ++r) {
            float w = __builtin_nontemporal_load(&Wih[(size_t)(g0 + r) * IND + INX + k]);
#pragma unroll
            for (int b = 0; b < 8; ++b) acc[r][b] = fmaf(w, mv[b], acc[r][b]);
        }
    }
    for (int j = tid; j < HH; j += 256) {
        float hv[8];
#pragma unroll
        for (int b = 0; b < 8; ++b) hv[b] = h[b * HH + j];
#pragma unroll
        for (int r = 0; r < 8; ++r) {
            float w = Whh[(size_t)(g0 + r) * HH + j];
#pragma unroll
            for (int b = 0; b < 8; ++b) acc[r][b] = fmaf(w, hv[b], acc[r][b]);
        }
    }
#pragma unroll
    for (int r = 0; r < 8; ++r)
#pragma unroll
        for (int b = 0; b < 8; ++b) {
            float v = acc[r][b];
            for (int off = 32; off; off >>= 1) v += __shfl_down(v, off, 64);
            acc[r][b] = v;
        }
    __shared__ float red[4][8][8];
    const int wave = tid >> 6, lane = tid & 63;
    if (lane == 0) {
#pragma unroll
        for (int r = 0; r < 8; ++r)
#pragma unroll
            for (int b = 0; b < 8; ++b) red[wave][r][b] = acc[r][b];
    }
    __syncthreads();
    if (tid < 64) {
        const int r = tid >> 3, b = tid & 7;
        const int g = g0 + r;
        float v = red[0][r][b] + red[1][r][b] + red[2][r][b] + red[3][r][b];
        gates[b * G4 + g] = v + bih[g] + bhh[g];
    }
}

__global__ void k_cell(const float* __restrict__ gates, float* __restrict__ c,
                       float* __restrict__ h, float* __restrict__ hrelu) {
    int idx = blockIdx.x * 256 + threadIdx.x;
    if (idx >= BB * HH) return;
    const int b = idx >> 10, j = idx & (HH - 1);
    const float* gb = gates + b * G4;
    float ig = sigf(gb[j]);
    float fg = sigf(gb[HH + j]);
    float gg = tanhf(gb[2 * HH + j]);
    float og = sigf(gb[3 * HH + j]);
    float cn = fg * c[idx] + ig * gg;
    float hn = og * tanhf(cn);
    c[idx] = cn;
    h[idx] = hn;
    hrelu[idx] = fmaxf(hn, 0.f);
}

__global__ __launch_bounds__(256)
void k_attout(const float* __restrict__ hrelu,
              const float* __restrict__ Watt, const float* __restrict__ batt,
              const float* __restrict__ Wout, const float* __restrict__ bout,
              float* __restrict__ att, float* __restrict__ out, int t) {
    const int wid = blockIdx.x * 4 + (threadIdx.x >> 6);
    const int lane = threadIdx.x & 63;
    if (wid >= 2 * AA) return;
    const bool isAtt = wid < AA;
    const int row = isAtt ? wid : wid - AA;
    const float* W = isAtt ? Watt : Wout;
    float acc[8];
#pragma unroll
    for (int b = 0; b < 8; ++b) acc[b] = 0.f;
    for (int j = lane; j < HH; j += 64) {
        const float w = W[(size_t)row * HH + j];
#pragma unroll
        for (int b = 0; b < 8; ++b) acc[b] = fmaf(w, hrelu[b * HH + j], acc[b]);
    }
#pragma unroll
    for (int b = 0; b < 8; ++b) {
        float v = acc[b];
        for (int off = 32; off; off >>= 1) v += __shfl_xor(v, off, 64);
        acc[b] = v;
    }
    if (lane < 8) {
        const int b = lane;
        if (isAtt)
            att[b * AA + row] = sigf(acc[b] + batt[row]);
        else
            out[((size_t)b * TT + t) * AA + row] = sigf(acc[b] + bout[row]);
    }
}

// ---------------------------------------------------------------------------
extern "C" void kernel_launch(void* const* d_in, const int* in_sizes, int n_in,
                              void* d_out, int out_size, void* d_ws, size_t ws_size,
                              hipStream_t stream) {
    const float* tensors = (const float*)d_in[0];
    const float* masks   = (const float*)d_in[1];
    const float* Wih     = (const float*)d_in[2];
    const float* Whh     = (const float*)d_in[3];
    const float* bih     = (const float*)d_in[4];
    const float* bhh     = (const float*)d_in[5];
    const float* Watt    = (const float*)d_in[6];
    const float* batt    = (const float*)d_in[7];
    const float* Wout    = (const float*)d_in[8];
    const float* bout    = (const float*)d_in[9];
    float* out = (float*)d_out;

    float* ws     = (float*)d_ws;
    float* h      = ws;                    // 8192
    float* c0     = h + BB * HH;           // 8192
    float* c1     = c0 + BB * HH;          // 8192
    float* hrelu  = c1 + BB * HH;          // 8192
    float* gates2 = hrelu + BB * HH;       // 32768
    float* att    = gates2 + BB * G4;      // 11552
    float* part   = att + BB * AA;         // 64*8*4096 = 2097152
    float* gm     = part + (size_t)SEG * BB * G4;  // 50*8*4096 = 1638400
    u16*   Wf     = (u16*)(gm + (size_t)TT * BB * G4);   // 769.1 MB
    u16*   Y      = Wf + (size_t)G4 * INDP;              // 4.73 GB

    const size_t f32_cnt = (size_t)(4 * BB * HH + BB * G4 + BB * AA)
                         + (size_t)SEG * BB * G4 + (size_t)TT * BB * G4;
    const size_t need = f32_cnt * 4 + (size_t)G4 * INDP * 2
                      + (size_t)TT * AA * BB * G4 * 2;
    const bool fast_path = ws_size >= need;

    k_init<<<46, 256, 0, stream>>>(h, c0, c1, att);
    if (fast_path) {
        k_cvtswz<<<NKB * 64, 256, 0, stream>>>(Wih, Wf);
        k_gm<<<512, 512, 0, stream>>>(Wih, masks, gm);
        k_pre<<<AA * 16, 256, 0, stream>>>(Wf, tensors, Y);
        for (int t = 0; t < TT; ++t) {
            float* cin  = (t & 1) ? c1 : c0;
            float* cout = (t & 1) ? c0 : c1;
            k_contract<<<768, 512, 0, stream>>>(Y, att, Whh, h, part, gates2, t);
            k_cell3<<<16, 512, 0, stream>>>(part, gm, gates2, bih, bhh, cin,
                                            cout, h, hrelu, t);
            k_post2<<<362, 512, 0, stream>>>(hrelu, Watt, batt, Wout, bout,
                                             att, out, t);
        }
    } else {
        for (int t = 0; t < TT; ++t) {
            k_gates_f32<<<512, 256, 0, stream>>>(tensors, masks, Wih, Whh, bih,
                                                 bhh, h, att, part, t);
            k_cell<<<32, 256, 0, stream>>>(part, c0, h, hrelu);
            k_attout<<<722, 256, 0, stream>>>(hrelu, Watt, batt, Wout, bout,
                                              att, out, t);
        }
    }
}